// Round 8
// baseline (124.782 us; speedup 1.0000x reference)
//
#include <hip/hip_runtime.h>

#define CONS_RATE 0.001f
#define CLAMP_V   10.0f

// e^(2s) = 2^(s * 2/ln2)
#define TWO_LOG2E 2.88539008177792681472f

#if defined(__has_builtin)
#  if __has_builtin(__builtin_amdgcn_exp2f)
#    define EXP2F(x) __builtin_amdgcn_exp2f(x)
#  endif
#endif
#ifndef EXP2F
#  define EXP2F(x) __expf(0.69314718055994530942f * (x))
#endif

typedef float f32x4 __attribute__((ext_vector_type(4)));

__device__ __forceinline__ float rf(float x) {
    // force wave-uniform value into an SGPR
    return __uint_as_float(__builtin_amdgcn_readfirstlane(__float_as_uint(x)));
}

// Per-element: out = clamp(w + 0.001*tanh(s)),
//   s = b2 + sum_j v_j * relu(a_j*w + c_j)
//   = P + Q*w + sum_j u_j*|w - t_j|   (abs identity; coeffs in SGPRs)
//
// Round-8 (= round-7 resubmit): FILL-MIMICKING TOPOLOGY. The only 6.3 TB/s
// kernels measured on this box (fillBufferAligned, m13 copy) run few waves/CU
// sweeping unbroken contiguous address runs. All our variants ran 49-100%
// occupancy with 4K-16K interleaved streams. Here: 2 blocks/CU (25% occ),
// each WAVE owns a contiguous 32KB run (1KB steps, zero gaps), depth-8
// register double-buffer (64KB outstanding/CU). If neutral-or-worse, the
// failure mode (VALU-issue-bound at 2 waves/SIMD) makes the kernel visible
// in the top-5 profile again -> counters either way.

__global__ __launch_bounds__(256) void ConsolidationDynamics_70068096467285_kernel(
    const float* __restrict__ w,
    const float* __restrict__ cs_p,
    const float* __restrict__ fs_p,
    const float* __restrict__ W1,   // (3,16) row-major
    const float* __restrict__ b1,   // (16,)
    const float* __restrict__ W2,   // (16,1)
    const float* __restrict__ b2,   // (1,)
    float* __restrict__ out,
    int n)
{
    const float cs = cs_p[0];
    const float fs = fs_p[0];

    float P = b2[0];
    float Q = 0.0f;

#define COEF(J) \
    float t##J, u##J; { \
        const float a = W1[J]; \
        const float v = W2[J]; \
        const float c = fmaf(cs, W1[16 + J], fmaf(fs, W1[32 + J], b1[J])); \
        P = fmaf(0.5f * v, c, P); \
        Q = fmaf(0.5f * v, a, Q); \
        if (a != 0.0f) { t##J = rf(-c / a); u##J = rf(0.5f * v * fabsf(a)); } \
        else { t##J = 0.0f; u##J = 0.0f; P = fmaf(v, fmaxf(c, 0.0f) - 0.5f * c, P); } \
    }
    COEF(0)  COEF(1)  COEF(2)  COEF(3)
    COEF(4)  COEF(5)  COEF(6)  COEF(7)
    COEF(8)  COEF(9)  COEF(10) COEF(11)
    COEF(12) COEF(13) COEF(14) COEF(15)
#undef COEF
    P = rf(P);
    Q = rf(Q);

#define TERM(J, sacc) sacc = fmaf(u##J, fabsf(t##J - r_), sacc);

#define EVAL(rr, d) { \
    const float r_ = (rr); \
    float s0 = fmaf(r_, Q, P); \
    float s1 = u1 * fabsf(t1 - r_); \
    TERM(0, s0)  TERM(2, s0)  TERM(3, s1)  TERM(4, s0)  TERM(5, s1) \
    TERM(6, s0)  TERM(7, s1)  TERM(8, s0)  TERM(9, s1)  TERM(10, s0) \
    TERM(11, s1) TERM(12, s0) TERM(13, s1) TERM(14, s0) TERM(15, s1) \
    const float e  = EXP2F((s0 + s1) * TWO_LOG2E); \
    const float u  = fmaf(-2.0f, __builtin_amdgcn_rcpf(e + 1.0f), 1.0f); \
    const float nw = fmaf(u, CONS_RATE, r_); \
    (d) = fminf(fmaxf(nw, -CLAMP_V), CLAMP_V); }

#define EVAL4(V, O) \
    EVAL((V).x, (O).x) EVAL((V).y, (O).y) EVAL((V).z, (O).z) EVAL((V).w, (O).w)

    const int n4 = n >> 2;                 // float4 count
    const f32x4* __restrict__ w4 = (const f32x4*)w;
    f32x4* __restrict__ o4 = (f32x4*)out;

    const int wid  = threadIdx.x >> 6;     // wave id 0..3
    const int lane = threadIdx.x & 63;
    // Block slab: 8192 float4 (128KB in). Each wave owns a CONTIGUOUS
    // quarter (2048 float4 = 32KB): address stream has zero gaps,
    // stepping 64 float4 (1KB) per k.
    const int slab = blockIdx.x << 13;
    const int base = slab + (wid << 11) + lane;

    if (slab + 8192 <= n4) {
        const f32x4* __restrict__ src = w4 + base;
        f32x4* __restrict__ dst = o4 + base;
        f32x4 b0[8], b1[8];

        // All indices compile-time constants -> arrays stay in registers.
#define LD8(BUF, OFF) \
        BUF[0] = src[(OFF + 0) << 6]; BUF[1] = src[(OFF + 1) << 6]; \
        BUF[2] = src[(OFF + 2) << 6]; BUF[3] = src[(OFF + 3) << 6]; \
        BUF[4] = src[(OFF + 4) << 6]; BUF[5] = src[(OFF + 5) << 6]; \
        BUF[6] = src[(OFF + 6) << 6]; BUF[7] = src[(OFF + 7) << 6];
#define CS1(BUF, OFF, J) { f32x4 o_; EVAL4(BUF[J], o_) \
        __builtin_nontemporal_store(o_, &dst[(OFF + J) << 6]); }
#define CSTORE(BUF, OFF) \
        CS1(BUF, OFF, 0) CS1(BUF, OFF, 1) CS1(BUF, OFF, 2) CS1(BUF, OFF, 3) \
        CS1(BUF, OFF, 4) CS1(BUF, OFF, 5) CS1(BUF, OFF, 6) CS1(BUF, OFF, 7)

        // Depth-8 register double-buffer: the next 8KB of loads is in
        // flight while the current 8 float4s are evaluated and stored.
        LD8(b0, 0)
        LD8(b1, 8)
        CSTORE(b0, 0)
        LD8(b0, 16)
        CSTORE(b1, 8)
        LD8(b1, 24)
        CSTORE(b0, 16)
        CSTORE(b1, 24)
#undef CSTORE
#undef CS1
#undef LD8
    } else {
        // Partial slab: guarded per-float4.
        for (int k = 0; k < 32; ++k) {
            const int idx = base + (k << 6);
            if (idx < n4) {
                const f32x4 A = w4[idx];
                f32x4 oA;
                EVAL4(A, oA)
                __builtin_nontemporal_store(oA, &o4[idx]);
            }
        }
    }
    // Scalar tail (n % 4), handled by block 0.
    if (blockIdx.x == 0) {
        const int rem = n & 3;
        if ((int)threadIdx.x < rem) {
            const float r = w[(n4 << 2) + threadIdx.x];
            float d;
            EVAL(r, d)
            out[(n4 << 2) + threadIdx.x] = d;
        }
    }
#undef EVAL4
#undef EVAL
#undef TERM
}

extern "C" void kernel_launch(void* const* d_in, const int* in_sizes, int n_in,
                              void* d_out, int out_size, void* d_ws, size_t ws_size,
                              hipStream_t stream) {
    const float* w   = (const float*)d_in[0];
    const float* cs  = (const float*)d_in[1];
    const float* fs  = (const float*)d_in[2];
    const float* W1  = (const float*)d_in[3];
    const float* b1  = (const float*)d_in[4];
    const float* W2  = (const float*)d_in[5];
    const float* b2  = (const float*)d_in[6];
    float* out = (float*)d_out;

    const int n  = in_sizes[0];
    const int n4 = n >> 2;
    // n=4096^2 -> 512 blocks = 2 blocks/CU (25% occupancy), each block a
    // contiguous 128KB-in slab, each wave a contiguous 32KB run.
    const int block = 256;
    int grid = (n4 + 8191) >> 13;
    if (grid < 1) grid = 1;

    ConsolidationDynamics_70068096467285_kernel<<<grid, block, 0, stream>>>(
        w, cs, fs, W1, b1, W2, b2, out, n);
}

// Round 10
// 124.695 us; speedup vs baseline: 1.0007x; 1.0007x over previous
//
#include <hip/hip_runtime.h>

#define CONS_RATE 0.001f
#define CLAMP_V   10.0f

// e^(2s) = 2^(s * 2/ln2)
#define TWO_LOG2E 2.88539008177792681472f

#if defined(__has_builtin)
#  if __has_builtin(__builtin_amdgcn_exp2f)
#    define EXP2F(x) __builtin_amdgcn_exp2f(x)
#  endif
#endif
#ifndef EXP2F
#  define EXP2F(x) __expf(0.69314718055994530942f * (x))
#endif

typedef float f32x4 __attribute__((ext_vector_type(4)));

__device__ __forceinline__ float rf(float x) {
    // force wave-uniform value into an SGPR
    return __uint_as_float(__builtin_amdgcn_readfirstlane(__float_as_uint(x)));
}

// Per-element: out = clamp(w + 0.001*tanh(s)),
//   s = b2 + sum_j v_j * relu(a_j*w + c_j)
//   = P + Q*w + sum_j u_j*|w - t_j|   (abs identity; coeffs in SGPRs)
//
// Round-10 (= round-9 resubmit): FORCE the register pipeline into the ISA.
// Round-8's counters showed VGPR_Count=36 for source code holding 64 VGPRs
// of pipeline buffer -> the backend's max-occupancy heuristic (8 waves/SIMD
// needs <=64 VGPR) SANK all prefetch loads back to their uses in every prior
// round; the per-wave-MLP axis was never actually in the compiled code.
// __launch_bounds__(256, 4) caps at 4 waves/SIMD = 128 VGPR budget, and the
// 16 loads are issued up-front into 16 NAMED f32x4 values (no arrays, rule
// #20) so the scheduler keeps them outstanding while compute drains vmcnt
// progressively. Decisive check: VGPR_Count ~90-110 in the profile.

__global__ __launch_bounds__(256, 4) void ConsolidationDynamics_70068096467285_kernel(
    const float* __restrict__ w,
    const float* __restrict__ cs_p,
    const float* __restrict__ fs_p,
    const float* __restrict__ W1,   // (3,16) row-major
    const float* __restrict__ b1,   // (16,)
    const float* __restrict__ W2,   // (16,1)
    const float* __restrict__ b2,   // (1,)
    float* __restrict__ out,
    int n)
{
    const float cs = cs_p[0];
    const float fs = fs_p[0];

    float P = b2[0];
    float Q = 0.0f;

#define COEF(J) \
    float t##J, u##J; { \
        const float a = W1[J]; \
        const float v = W2[J]; \
        const float c = fmaf(cs, W1[16 + J], fmaf(fs, W1[32 + J], b1[J])); \
        P = fmaf(0.5f * v, c, P); \
        Q = fmaf(0.5f * v, a, Q); \
        if (a != 0.0f) { t##J = rf(-c / a); u##J = rf(0.5f * v * fabsf(a)); } \
        else { t##J = 0.0f; u##J = 0.0f; P = fmaf(v, fmaxf(c, 0.0f) - 0.5f * c, P); } \
    }
    COEF(0)  COEF(1)  COEF(2)  COEF(3)
    COEF(4)  COEF(5)  COEF(6)  COEF(7)
    COEF(8)  COEF(9)  COEF(10) COEF(11)
    COEF(12) COEF(13) COEF(14) COEF(15)
#undef COEF
    P = rf(P);
    Q = rf(Q);

#define TERM(J, sacc) sacc = fmaf(u##J, fabsf(t##J - r_), sacc);

#define EVAL(rr, d) { \
    const float r_ = (rr); \
    float s0 = fmaf(r_, Q, P); \
    float s1 = u1 * fabsf(t1 - r_); \
    TERM(0, s0)  TERM(2, s0)  TERM(3, s1)  TERM(4, s0)  TERM(5, s1) \
    TERM(6, s0)  TERM(7, s1)  TERM(8, s0)  TERM(9, s1)  TERM(10, s0) \
    TERM(11, s1) TERM(12, s0) TERM(13, s1) TERM(14, s0) TERM(15, s1) \
    const float e  = EXP2F((s0 + s1) * TWO_LOG2E); \
    const float u  = fmaf(-2.0f, __builtin_amdgcn_rcpf(e + 1.0f), 1.0f); \
    const float nw = fmaf(u, CONS_RATE, r_); \
    (d) = fminf(fmaxf(nw, -CLAMP_V), CLAMP_V); }

#define EVAL4(V, O) \
    EVAL((V).x, (O).x) EVAL((V).y, (O).y) EVAL((V).z, (O).z) EVAL((V).w, (O).w)

    const int n4 = n >> 2;                 // float4 count
    const f32x4* __restrict__ w4 = (const f32x4*)w;
    f32x4* __restrict__ o4 = (f32x4*)out;

    const int wid  = threadIdx.x >> 6;     // wave id 0..3
    const int lane = threadIdx.x & 63;
    // Block slab: 4096 float4 (64KB in). Each wave owns a contiguous
    // 1024-float4 (16KB) run, stepping 64 float4 (1KB) per stage.
    const int slab = blockIdx.x << 12;
    const int base = slab + (wid << 10) + lane;

    if (slab + 4096 <= n4) {
        const f32x4* __restrict__ src = w4 + base;
        f32x4* __restrict__ dst = o4 + base;

        // Phase 1: issue ALL 16 loads (64 VGPRs live, 16KB/wave in flight).
        const f32x4 d0  = src[ 0 << 6];
        const f32x4 d1  = src[ 1 << 6];
        const f32x4 d2  = src[ 2 << 6];
        const f32x4 d3  = src[ 3 << 6];
        const f32x4 d4  = src[ 4 << 6];
        const f32x4 d5  = src[ 5 << 6];
        const f32x4 d6  = src[ 6 << 6];
        const f32x4 d7  = src[ 7 << 6];
        const f32x4 d8  = src[ 8 << 6];
        const f32x4 d9  = src[ 9 << 6];
        const f32x4 d10 = src[10 << 6];
        const f32x4 d11 = src[11 << 6];
        const f32x4 d12 = src[12 << 6];
        const f32x4 d13 = src[13 << 6];
        const f32x4 d14 = src[14 << 6];
        const f32x4 d15 = src[15 << 6];

        // Phase 2: compute+store in load order; the compiler's waitcnt
        // drains vmcnt progressively (vmcnt(15), (14), ...) while the
        // remaining loads stay outstanding under the compute.
#define CS(K) { f32x4 o_; EVAL4(d##K, o_) \
        __builtin_nontemporal_store(o_, &dst[K << 6]); }
        CS(0)  CS(1)  CS(2)  CS(3)
        CS(4)  CS(5)  CS(6)  CS(7)
        CS(8)  CS(9)  CS(10) CS(11)
        CS(12) CS(13) CS(14) CS(15)
#undef CS
    } else {
        // Partial slab: guarded per-float4.
        for (int k = 0; k < 16; ++k) {
            const int idx = base + (k << 6);
            if (idx < n4) {
                const f32x4 A = w4[idx];
                f32x4 oA;
                EVAL4(A, oA)
                __builtin_nontemporal_store(oA, &o4[idx]);
            }
        }
    }
    // Scalar tail (n % 4), handled by block 0.
    if (blockIdx.x == 0) {
        const int rem = n & 3;
        if ((int)threadIdx.x < rem) {
            const float r = w[(n4 << 2) + threadIdx.x];
            float d;
            EVAL(r, d)
            out[(n4 << 2) + threadIdx.x] = d;
        }
    }
#undef EVAL4
#undef EVAL
#undef TERM
}

extern "C" void kernel_launch(void* const* d_in, const int* in_sizes, int n_in,
                              void* d_out, int out_size, void* d_ws, size_t ws_size,
                              hipStream_t stream) {
    const float* w   = (const float*)d_in[0];
    const float* cs  = (const float*)d_in[1];
    const float* fs  = (const float*)d_in[2];
    const float* W1  = (const float*)d_in[3];
    const float* b1  = (const float*)d_in[4];
    const float* W2  = (const float*)d_in[5];
    const float* b2  = (const float*)d_in[6];
    float* out = (float*)d_out;

    const int n  = in_sizes[0];
    const int n4 = n >> 2;
    // n=4096^2 -> 1024 blocks = 4 blocks/CU, matching the 4-waves/SIMD
    // launch bound exactly; one residency round; 16 float4/thread one-shot.
    const int block = 256;
    int grid = (n4 + 4095) >> 12;
    if (grid < 1) grid = 1;

    ConsolidationDynamics_70068096467285_kernel<<<grid, block, 0, stream>>>(
        w, cs, fs, W1, b1, W2, b2, out, n);
}

// Round 11
// 124.551 us; speedup vs baseline: 1.0018x; 1.0011x over previous
//
#include <hip/hip_runtime.h>

#define CONS_RATE 0.001f
#define CLAMP_V   10.0f

// e^(2s) = 2^(s * 2/ln2)
#define TWO_LOG2E 2.88539008177792681472f

#if defined(__has_builtin)
#  if __has_builtin(__builtin_amdgcn_exp2f)
#    define EXP2F(x) __builtin_amdgcn_exp2f(x)
#  endif
#endif
#ifndef EXP2F
#  define EXP2F(x) __expf(0.69314718055994530942f * (x))
#endif

typedef float f32x4 __attribute__((ext_vector_type(4)));

__device__ __forceinline__ float rf(float x) {
    return __uint_as_float(__builtin_amdgcn_readfirstlane(__float_as_uint(x)));
}

// Round-11: LUT compute. cs/fs are launch constants, so
//   update(w) = 0.001*tanh(P + Q*w + sum_j u_j*|w - t_j|)
// is a FIXED 1-D function per launch. Build a 2049-sample table over
// [-10.24, 10.24] (h = 0.01) in LDS once per block, then each element is
// ~11 VALU + one ds_read2_b32 (PWL interp) instead of ~41 VALU + 2
// transcendentals. Interp error <= ~1e-6 (kink error |u|*h/4*1e-3), far
// below the ~1e-3 margin the direct version passes with.
// Topology is held identical to the round-6 baseline (1024 blocks,
// contiguous slabs, 16 float4/thread) -> clean A/B on the compute axis.

#define TAB_N   2048
#define TAB_H   0.01f
#define TAB_X0  -10.24f
#define TAB_INVH 100.0f
#define TAB_OFF  1024.0f       // (w - TAB_X0) / h = w*100 + 1024

__global__ __launch_bounds__(256) void ConsolidationDynamics_70068096467285_kernel(
    const float* __restrict__ w,
    const float* __restrict__ cs_p,
    const float* __restrict__ fs_p,
    const float* __restrict__ W1,   // (3,16) row-major
    const float* __restrict__ b1,   // (16,)
    const float* __restrict__ W2,   // (16,1)
    const float* __restrict__ b2,   // (1,)
    float* __restrict__ out,
    int n)
{
    __shared__ float tab[TAB_N + 1];

    const float cs = cs_p[0];
    const float fs = fs_p[0];

    float P = b2[0];
    float Q = 0.0f;

#define COEF(J) \
    float t##J, u##J; { \
        const float a = W1[J]; \
        const float v = W2[J]; \
        const float c = fmaf(cs, W1[16 + J], fmaf(fs, W1[32 + J], b1[J])); \
        P = fmaf(0.5f * v, c, P); \
        Q = fmaf(0.5f * v, a, Q); \
        if (a != 0.0f) { t##J = rf(-c / a); u##J = rf(0.5f * v * fabsf(a)); } \
        else { t##J = 0.0f; u##J = 0.0f; P = fmaf(v, fmaxf(c, 0.0f) - 0.5f * c, P); } \
    }
    COEF(0)  COEF(1)  COEF(2)  COEF(3)
    COEF(4)  COEF(5)  COEF(6)  COEF(7)
    COEF(8)  COEF(9)  COEF(10) COEF(11)
    COEF(12) COEF(13) COEF(14) COEF(15)
#undef COEF
    P = rf(P);
    Q = rf(Q);

#define TERM(J, sacc) sacc = fmaf(u##J, fabsf(t##J - r_), sacc);

    // Build the update table: 2049 samples, 8-9 per thread, one-time
    // (~12.5% of the direct per-element EVAL work, VALU-only, overlaps
    // with nothing downstream until the barrier).
    for (int i = threadIdx.x; i <= TAB_N; i += 256) {
        const float r_ = fmaf((float)i, TAB_H, TAB_X0);
        float s0 = fmaf(r_, Q, P);
        float s1 = u1 * fabsf(t1 - r_);
        TERM(0, s0)  TERM(2, s0)  TERM(3, s1)  TERM(4, s0)  TERM(5, s1)
        TERM(6, s0)  TERM(7, s1)  TERM(8, s0)  TERM(9, s1)  TERM(10, s0)
        TERM(11, s1) TERM(12, s0) TERM(13, s1) TERM(14, s0) TERM(15, s1)
        const float e  = EXP2F((s0 + s1) * TWO_LOG2E);
        const float uu = fmaf(-2.0f, __builtin_amdgcn_rcpf(e + 1.0f), 1.0f);
        tab[i] = uu * CONS_RATE;     // update(w), CONS_RATE baked in
    }
    __syncthreads();
#undef TERM

    // Per-element lookup: ~11 VALU + ds_read2_b32.
    // Index clamp to [0, 2047.9] keeps idx+1 in range; for |w| beyond the
    // table the final +/-10 clamp dominates (|update| <= 1e-3), so the
    // result is exact there too.
#define LOOK(wv, d) { \
    float idxf = fmaf((wv), TAB_INVH, TAB_OFF); \
    idxf = fminf(fmaxf(idxf, 0.0f), 2047.9f); \
    const int   ix = (int)idxf; \
    const float fr = idxf - (float)ix; \
    const float g0 = tab[ix]; \
    const float g1 = tab[ix + 1]; \
    const float nw = (wv) + fmaf(g1 - g0, fr, g0); \
    (d) = fminf(fmaxf(nw, -CLAMP_V), CLAMP_V); }

#define LOOK4(V, O) \
    LOOK((V).x, (O).x) LOOK((V).y, (O).y) LOOK((V).z, (O).z) LOOK((V).w, (O).w)

    const int n4 = n >> 2;
    const f32x4* __restrict__ w4 = (const f32x4*)w;
    f32x4* __restrict__ o4 = (f32x4*)out;

    const int tid  = threadIdx.x;
    const int slab = blockIdx.x << 12;           // 4096 float4 per block

    if (slab + 4096 <= n4) {
#pragma unroll 4
        for (int k = 0; k < 16; ++k) {
            const int idx = slab + (k << 8) + tid;
            const f32x4 A = w4[idx];
            f32x4 oA;
            LOOK4(A, oA)
            __builtin_nontemporal_store(oA, &o4[idx]);
        }
    } else {
        for (int k = 0; k < 16; ++k) {
            const int idx = slab + (k << 8) + tid;
            if (idx < n4) {
                const f32x4 A = w4[idx];
                f32x4 oA;
                LOOK4(A, oA)
                __builtin_nontemporal_store(oA, &o4[idx]);
            }
        }
    }
    // Scalar tail (n % 4), block 0.
    if (blockIdx.x == 0) {
        const int rem = n & 3;
        if (tid < rem) {
            const float r = w[(n4 << 2) + tid];
            float d;
            LOOK(r, d)
            out[(n4 << 2) + tid] = d;
        }
    }
#undef LOOK4
#undef LOOK
}

extern "C" void kernel_launch(void* const* d_in, const int* in_sizes, int n_in,
                              void* d_out, int out_size, void* d_ws, size_t ws_size,
                              hipStream_t stream) {
    const float* w   = (const float*)d_in[0];
    const float* cs  = (const float*)d_in[1];
    const float* fs  = (const float*)d_in[2];
    const float* W1  = (const float*)d_in[3];
    const float* b1  = (const float*)d_in[4];
    const float* W2  = (const float*)d_in[5];
    const float* b2  = (const float*)d_in[6];
    float* out = (float*)d_out;

    const int n  = in_sizes[0];
    const int n4 = n >> 2;
    // Same topology as round 6: 1024 blocks (4/CU, 16 waves/CU), each a
    // contiguous 64KB-in slab; only the compute path changed (EVAL -> LUT).
    const int block = 256;
    int grid = (n4 + 4095) >> 12;
    if (grid < 1) grid = 1;

    ConsolidationDynamics_70068096467285_kernel<<<grid, block, 0, stream>>>(
        w, cs, fs, W1, b1, W2, b2, out, n);
}